// Round 8
// baseline (509.896 us; speedup 1.0000x reference)
//
#include <hip/hip_runtime.h>
#include <hip/hip_fp16.h>

#define B_ 256
#define T_ 512
#define H_ 128
#define M_ (B_ * T_)  // 131072 rows

typedef _Float16 f16x8 __attribute__((ext_vector_type(8)));
typedef float    f32x4 __attribute__((ext_vector_type(4)));

__device__ __forceinline__ float rcp_f(float a) { return __builtin_amdgcn_rcpf(a); }
__device__ __forceinline__ float sigmoid_f(float a) { return rcp_f(1.f + __expf(-a)); }
__device__ __forceinline__ float tanh_f(float a) { return 1.f - 2.f * rcp_f(__expf(2.f * a) + 1.f); }

// LDS-only barrier: global loads/stores stay in flight (T4: never vmcnt(0) per step).
__device__ __forceinline__ void lds_barrier() {
    asm volatile("s_waitcnt lgkmcnt(0)\n\ts_barrier" ::: "memory");
}

__device__ __forceinline__ __half cell_update(float g0, float g1, float g2, float g3, float& c) {
    float iv = sigmoid_f(g0), fv = sigmoid_f(g1);
    float gv = tanh_f(g2),   ov = sigmoid_f(g3);
    c = fv * c + iv * gv;
    return __float2half(ov * tanh_f(c));
}

// ---- device-visible (cross-XCD via L3) memory ops: sc0 sc1 ----
__device__ __forceinline__ void store_dwordx2_sc(uint64_t addr, uint2 v) {
    asm volatile("global_store_dwordx2 %0, %1, off sc0 sc1" :: "v"(addr), "v"(v) : "memory");
}
__device__ __forceinline__ void store_flag_sc(uint64_t addr, unsigned v) {
    asm volatile("global_store_dword %0, %1, off sc0 sc1" :: "v"(addr), "v"(v) : "memory");
}
__device__ __forceinline__ unsigned load_flag_sc(uint64_t addr) {
    unsigned v;
    asm volatile("global_load_dword %0, %1, off sc0 sc1\n\ts_waitcnt vmcnt(0)"
                 : "=v"(v) : "v"(addr) : "memory");
    return v;
}
#define LOAD8_SC(dst, addr) \
    asm volatile("global_load_dwordx2 %0, %1, off sc0 sc1" : "=&v"(dst) : "v"(addr) : "memory")

#define MFMA16(A, BV, C) __builtin_amdgcn_mfma_f32_16x16x32_f16((A), (BV), (C), 0, 0, 0)
#define MF4(AV, WARR, KT) \
    ac0 = MFMA16(AV, WARR[0][KT], ac0); \
    ac1 = MFMA16(AV, WARR[1][KT], ac1); \
    ac2 = MFMA16(AV, WARR[2][KT], ac2); \
    ac3 = MFMA16(AV, WARR[3][KT], ac3);
#define PF4(AV, KT) \
    px0 = MFMA16(AV, wi[0][KT], px0); \
    px1 = MFMA16(AV, wi[1][KT], px1); \
    px2 = MFMA16(AV, wi[2][KT], px2); \
    px3 = MFMA16(AV, wi[3][KT], px3);

// ---------- one-time conversions ----------
__global__ __launch_bounds__(256)
void convert_kernel(const float* __restrict__ Wih0, const float* __restrict__ bih0, const float* __restrict__ bhh0,
                    const float* __restrict__ Whh0, const float* __restrict__ Wih1, const float* __restrict__ Whh1,
                    const float* __restrict__ bih1, const float* __restrict__ bhh1,
                    const float* __restrict__ Wl, const float* __restrict__ bl,
                    const float* __restrict__ Wo, const float* __restrict__ bo,
                    __half* __restrict__ W0b, __half* __restrict__ W1b,
                    __half* __restrict__ Whh0h, __half* __restrict__ Whh1h,
                    __half* __restrict__ Wc16, float* __restrict__ b0, float* __restrict__ b1,
                    float* __restrict__ bc)
{
    const int tid = threadIdx.x, bid = blockIdx.x;
    if (bid == 0) {
        for (int i = tid; i < 512; i += 256) { b0[i] = bih0[i] + bhh0[i]; b1[i] = bih1[i] + bhh1[i]; }
        for (int i = tid; i < 512 * 32; i += 256) {
            int r = i >> 5, k = i & 31;
            W0b[i] = __float2half(k < 30 ? Wih0[r * 30 + k] : 0.f);
        }
        for (int i = tid; i < 64 * 128; i += 256) {
            int j = i >> 7, k = i & 127;
            float a = 0.f;
            if (j < 63) for (int m = 0; m < 84; ++m) a += Wo[j * 84 + m] * Wl[m * 128 + k];
            Wc16[i] = __float2half(a);
        }
        if (tid < 64) {
            float a = 0.f;
            if (tid < 63) { a = bo[tid]; for (int m = 0; m < 84; ++m) a += Wo[tid * 84 + m] * bl[m]; }
            bc[tid] = a;
        }
    } else if (bid == 1) {
        for (int i = tid; i < 512 * 128; i += 256) W1b[i] = __float2half(Wih1[i]);
    } else if (bid == 2) {
        for (int i = tid; i < 512 * 128; i += 256) Whh0h[i] = __float2half(Whh0[i]);
    } else {
        for (int i = tid; i < 512 * 128; i += 256) Whh1h[i] = __float2half(Whh1[i]);
    }
}

// ---------- fused dual-layer recurrence ----------
// blocks 0-63: layer0 + on-the-fly xp1 = Wih1@h1 + b1 (gate-interleaved sc-store)
// blocks 64-127: layer1 rec consuming xp1 with 4-deep counted-vmcnt pipeline
__global__ __launch_bounds__(512)
__attribute__((amdgpu_waves_per_eu(2, 2)))
void lstm_fused(const float* __restrict__ x,
                const __half* __restrict__ W0b, const __half* __restrict__ Whh0h,
                const __half* __restrict__ W1b, const __half* __restrict__ Whh1h,
                const float* __restrict__ b0, const float* __restrict__ b1,
                __half* __restrict__ xp, __half* __restrict__ h2g,
                unsigned* __restrict__ flags)
{
    const int bid = blockIdx.x;
    const bool producer = bid < 64;
    const int g = bid & 63;           // batch group: batches 4g..4g+3
    const int tid = threadIdx.x;
    const int w = tid >> 6;           // wave -> units 16w..16w+15
    const int lane = tid & 63;
    const int l15 = lane & 15, qg = lane >> 4;
    const int j = w * 16 + l15;       // this lane's unit
    const int r = l15 >> 2;           // A-row batch (duplicated 4x -> LDS broadcast)

    // h tile: [4 batches][128 units] fp16, row stride 320B
    __shared__ __align__(16) char hbuf_s[2][1280];
    __shared__ __align__(16) __half xl[4][129][32];  // producer x chunk (pad row vs bank align)
    char* const hb0 = hbuf_s[0];
    char* const hb1 = hbuf_s[1];

    const int ro0 = r * 320 + 0 * 64 + qg * 16;
    const int ro1 = r * 320 + 1 * 64 + qg * 16;
    const int ro2 = r * 320 + 2 * 64 + qg * 16;
    const int ro3 = r * 320 + 3 * 64 + qg * 16;
    const int wo  = qg * 320 + j * 2;

    for (int i = tid; i < 320; i += 512) ((unsigned*)hb0)[i] = 0;  // h(-1) = 0

    float c = 0.f;
    f16x8 wb[4][4];

    if (producer) {
        float bias4[4], b14[4];
        f16x8 wx[4], wi[4][4];
#pragma unroll
        for (int q = 0; q < 4; ++q) {
            bias4[q] = b0[q * 128 + j];
            b14[q]   = b1[q * 128 + j];
            wx[q] = *reinterpret_cast<const f16x8*>(W0b + (size_t)(q * 128 + j) * 32 + qg * 8);
#pragma unroll
            for (int kt = 0; kt < 4; ++kt) {
                wb[q][kt] = *reinterpret_cast<const f16x8*>(Whh0h + (size_t)(q * 128 + j) * 128 + kt * 32 + qg * 8);
                wi[q][kt] = *reinterpret_cast<const f16x8*>(W1b   + (size_t)(q * 128 + j) * 128 + kt * 32 + qg * 8);
            }
        }
        // zero the x padding columns (30,31) once
        for (int idx = tid; idx < 1024; idx += 512) {
            int b4 = idx >> 8, rest = idx & 255;
            xl[b4][rest >> 1][30 + (rest & 1)] = __float2half(0.f);
        }
        const int b = g * 4 + qg;
        const uint64_t xpsb = (uint64_t)(uintptr_t)xp + (((uint64_t)b * T_) * 512 + 4 * j) * 2;
        const uint64_t flagaddr = (uint64_t)(uintptr_t)(flags + (g * 8 + w));
        const char* xlb = (const char*)xl;
        const int xro = r * 8256 + qg * 16;
        __syncthreads();

#define PSTEP(TT, RB, WB) do {                                                  \
        const int ts_ = (TT);                                                   \
        const int t_ = cbase + ts_;                                             \
        const char* rp_ = (RB) ? hb1 : hb0;                                     \
        char* wp_ = (WB) ? hb1 : hb0;                                           \
        f16x8 a0_ = *(const f16x8*)(rp_ + ro0);                                 \
        f16x8 a1_ = *(const f16x8*)(rp_ + ro1);                                 \
        f16x8 a2_ = *(const f16x8*)(rp_ + ro2);                                 \
        f16x8 a3_ = *(const f16x8*)(rp_ + ro3);                                 \
        f16x8 ax_ = *(const f16x8*)(xlb + (xro + ts_ * 64));                    \
        f32x4 ac0 = (f32x4){bias4[0], 0.f, 0.f, 0.f};                           \
        f32x4 ac1 = (f32x4){bias4[1], 0.f, 0.f, 0.f};                           \
        f32x4 ac2 = (f32x4){bias4[2], 0.f, 0.f, 0.f};                           \
        f32x4 ac3 = (f32x4){bias4[3], 0.f, 0.f, 0.f};                           \
        ac0 = MFMA16(ax_, wx[0], ac0); ac1 = MFMA16(ax_, wx[1], ac1);           \
        ac2 = MFMA16(ax_, wx[2], ac2); ac3 = MFMA16(ax_, wx[3], ac3);           \
        MF4(a0_, wb, 0) MF4(a1_, wb, 1) MF4(a2_, wb, 2) MF4(a3_, wb, 3)         \
        f32x4 px0 = (f32x4){b14[0], 0.f, 0.f, 0.f};                             \
        f32x4 px1 = (f32x4){b14[1], 0.f, 0.f, 0.f};                             \
        f32x4 px2 = (f32x4){b14[2], 0.f, 0.f, 0.f};                             \
        f32x4 px3 = (f32x4){b14[3], 0.f, 0.f, 0.f};                             \
        PF4(a0_, 0) PF4(a1_, 1) PF4(a2_, 2) PF4(a3_, 3)                         \
        __half hh_ = cell_update(ac0[0], ac1[0], ac2[0], ac3[0], c);            \
        *(__half*)(wp_ + wo) = hh_;                                             \
        if (t_ > 0) {                                                           \
            __half2 lo_ = __floats2half2_rn(px0[0], px1[0]);                    \
            __half2 hi_ = __floats2half2_rn(px2[0], px3[0]);                    \
            uint2 pk_;                                                          \
            pk_.x = __builtin_bit_cast(unsigned, lo_);                          \
            pk_.y = __builtin_bit_cast(unsigned, hi_);                          \
            store_dwordx2_sc(xpsb + (uint64_t)(t_ - 1) * 1024, pk_);            \
        }                                                                       \
        if ((t_ & 7) == 7) {                                                    \
            asm volatile("s_waitcnt vmcnt(0)" ::: "memory");                    \
            if (lane == 0) store_flag_sc(flagaddr, (unsigned)t_);               \
        }                                                                       \
        lds_barrier();                                                          \
    } while (0)

        for (int chunk = 0; chunk < 4; ++chunk) {
            const int cbase = chunk << 7;
#pragma unroll 1
            for (int b4 = 0; b4 < 4; ++b4) {
                const float* src = x + ((size_t)(g * 4 + b4) * T_ + cbase) * 30;
                for (int idx = tid; idx < 3840; idx += 512) {
                    int tt = idx / 30, ii = idx - tt * 30;
                    xl[b4][tt][ii] = __float2half(src[idx]);
                }
            }
            __syncthreads();
            for (int ts = 0; ts < 128; ts += 2) {
                PSTEP(ts, 0, 1);
                PSTEP(ts + 1, 1, 0);
            }
        }
        // epilogue: xp1(511) from h1(511) (in hb0 after step 511)
        {
            f16x8 a0_ = *(const f16x8*)(hb0 + ro0);
            f16x8 a1_ = *(const f16x8*)(hb0 + ro1);
            f16x8 a2_ = *(const f16x8*)(hb0 + ro2);
            f16x8 a3_ = *(const f16x8*)(hb0 + ro3);
            f32x4 px0 = (f32x4){b14[0], 0.f, 0.f, 0.f};
            f32x4 px1 = (f32x4){b14[1], 0.f, 0.f, 0.f};
            f32x4 px2 = (f32x4){b14[2], 0.f, 0.f, 0.f};
            f32x4 px3 = (f32x4){b14[3], 0.f, 0.f, 0.f};
            PF4(a0_, 0) PF4(a1_, 1) PF4(a2_, 2) PF4(a3_, 3)
            __half2 lo_ = __floats2half2_rn(px0[0], px1[0]);
            __half2 hi_ = __floats2half2_rn(px2[0], px3[0]);
            uint2 pk_;
            pk_.x = __builtin_bit_cast(unsigned, lo_);
            pk_.y = __builtin_bit_cast(unsigned, hi_);
            store_dwordx2_sc(xpsb + (uint64_t)511 * 1024, pk_);
            asm volatile("s_waitcnt vmcnt(0)" ::: "memory");
            if (lane == 0) store_flag_sc(flagaddr, 512u);
        }
    } else {
        // consumer: Whh1 only (light branch, no remat pressure)
#pragma unroll
        for (int q = 0; q < 4; ++q)
#pragma unroll
            for (int kt = 0; kt < 4; ++kt)
                wb[q][kt] = *reinterpret_cast<const f16x8*>(Whh1h + (size_t)(q * 128 + j) * 128 + kt * 32 + qg * 8);

        const int b = g * 4 + qg;
        const uint64_t xpcb = (uint64_t)(uintptr_t)xp + (((uint64_t)b * T_) * 512 + 4 * j) * 2;
        const uint64_t flagbase = (uint64_t)(uintptr_t)(flags + g * 8);
        __half* h2p = h2g + ((size_t)b * T_) * H_ + j;
        uint2 xq0, xq1, xq2, xq3;
        __syncthreads();

// per-step vmem per lane: exactly 1 load (L(t+4)) + 1 store (h2) -> counted wait:
// ops after L(t): S(t-4),L(t+1),S(t-3),L(t+2),S(t-2),L(t+3),S(t-1) = 7 -> vmcnt(7)
#define CSTEP(KK, XQ) do {                                                      \
        const int t_ = tg + (KK);                                               \
        const char* rp_ = (t_ & 1) ? hb1 : hb0;                                 \
        char* wp_ = (t_ & 1) ? hb0 : hb1;                                       \
        asm volatile("s_waitcnt vmcnt(7)" ::: "memory");                        \
        __builtin_amdgcn_sched_barrier(0);                                      \
        float2 flo = __half22float2(__builtin_bit_cast(__half2, XQ.x));         \
        float2 fhi = __half22float2(__builtin_bit_cast(__half2, XQ.y));         \
        LOAD8_SC(XQ, xpcb + (uint64_t)(t_ + 4) * 1024);                         \
        f16x8 a0_ = *(const f16x8*)(rp_ + ro0);                                 \
        f16x8 a1_ = *(const f16x8*)(rp_ + ro1);                                 \
        f16x8 a2_ = *(const f16x8*)(rp_ + ro2);                                 \
        f16x8 a3_ = *(const f16x8*)(rp_ + ro3);                                 \
        f32x4 ac0 = (f32x4){flo.x, 0.f, 0.f, 0.f};                              \
        f32x4 ac1 = (f32x4){flo.y, 0.f, 0.f, 0.f};                              \
        f32x4 ac2 = (f32x4){fhi.x, 0.f, 0.f, 0.f};                              \
        f32x4 ac3 = (f32x4){fhi.y, 0.f, 0.f, 0.f};                              \
        MF4(a0_, wb, 0) MF4(a1_, wb, 1) MF4(a2_, wb, 2) MF4(a3_, wb, 3)         \
        __half hh_ = cell_update(ac0[0], ac1[0], ac2[0], ac3[0], c);            \
        *(__half*)(wp_ + wo) = hh_;                                             \
        h2p[(size_t)t_ * H_] = hh_;                                             \
        lds_barrier();                                                          \
    } while (0)

        for (int tg = 0; tg < T_; tg += 16) {
            int tv = tg + 20; if (tv > 512) tv = 512;
            const unsigned target = (unsigned)tv;
            for (;;) {
                unsigned v = 0xFFFFFFFFu;
                if (lane < 8) v = load_flag_sc(flagbase + (uint64_t)lane * 4);
                v = min(v, (unsigned)__shfl_xor((int)v, 1));
                v = min(v, (unsigned)__shfl_xor((int)v, 2));
                v = min(v, (unsigned)__shfl_xor((int)v, 4));
                unsigned seen = (unsigned)__shfl((int)v, 0);
                if (seen >= target) break;
                __builtin_amdgcn_s_sleep(4);
            }
            if (tg == 0) {  // preload ring, drain once
                LOAD8_SC(xq0, xpcb + 0 * 1024);
                LOAD8_SC(xq1, xpcb + 1 * 1024);
                LOAD8_SC(xq2, xpcb + 2 * 1024);
                LOAD8_SC(xq3, xpcb + 3 * 1024);
                asm volatile("s_waitcnt vmcnt(0)" ::: "memory");
                __builtin_amdgcn_sched_barrier(0);
            }
            CSTEP(0, xq0);  CSTEP(1, xq1);  CSTEP(2, xq2);  CSTEP(3, xq3);
            CSTEP(4, xq0);  CSTEP(5, xq1);  CSTEP(6, xq2);  CSTEP(7, xq3);
            CSTEP(8, xq0);  CSTEP(9, xq1);  CSTEP(10, xq2); CSTEP(11, xq3);
            CSTEP(12, xq0); CSTEP(13, xq1); CSTEP(14, xq2); CSTEP(15, xq3);
        }
    }
}

// ---------- head: out = h2 @ Wc^T + bc (63 cols, f32) ----------
__global__ __launch_bounds__(256, 4)
void head_kernel(const __half* __restrict__ in, const __half* __restrict__ W16,
                 const float* __restrict__ bias, float* __restrict__ outp)
{
    constexpr int KK = 128;
    const int lane = threadIdx.x & 63;
    const int wn = threadIdx.x >> 6;
    const int rowbase = blockIdx.x * 64;  // ROWT=4
    const int colbase = wn * 16;
    const int l15 = lane & 15, lk = (lane >> 4) * 8;

    float bcol = bias[colbase + l15];
    f32x4 acc[4];
#pragma unroll
    for (int rt = 0; rt < 4; ++rt) acc[rt] = (f32x4){0.f, 0.f, 0.f, 0.f};

#pragma unroll
    for (int kt = 0; kt < 4; ++kt) {
        f16x8 bv = *reinterpret_cast<const f16x8*>(W16 + (size_t)(colbase + l15) * KK + kt * 32 + lk);
#pragma unroll
        for (int rt = 0; rt < 4; ++rt) {
            f16x8 a = *reinterpret_cast<const f16x8*>(in + (size_t)(rowbase + rt * 16 + l15) * KK + kt * 32 + lk);
            acc[rt] = __builtin_amdgcn_mfma_f32_16x16x32_f16(a, bv, acc[rt], 0, 0, 0);
        }
    }
    const int col = colbase + l15;
#pragma unroll
    for (int rt = 0; rt < 4; ++rt)
#pragma unroll
        for (int rr = 0; rr < 4; ++rr) {
            const int row = rowbase + rt * 16 + (lane >> 4) * 4 + rr;
            if (col < 63) outp[(size_t)row * 63 + col] = acc[rt][rr] + bcol;
        }
}

extern "C" void kernel_launch(void* const* d_in, const int* in_sizes, int n_in,
                              void* d_out, int out_size, void* d_ws, size_t ws_size,
                              hipStream_t stream)
{
    const float* x    = (const float*)d_in[0];
    const float* Wih0 = (const float*)d_in[1];
    const float* Whh0 = (const float*)d_in[2];
    const float* bih0 = (const float*)d_in[3];
    const float* bhh0 = (const float*)d_in[4];
    const float* Wih1 = (const float*)d_in[5];
    const float* Whh1 = (const float*)d_in[6];
    const float* bih1 = (const float*)d_in[7];
    const float* bhh1 = (const float*)d_in[8];
    const float* Wl   = (const float*)d_in[9];
    const float* bl   = (const float*)d_in[10];
    const float* Wo   = (const float*)d_in[11];
    const float* bo   = (const float*)d_in[12];
    float* out = (float*)d_out;

    char* ws = (char*)d_ws;
    size_t off = 0;
    auto carve = [&](size_t bytes) { void* p = ws + off; off += (bytes + 255) & ~(size_t)255; return p; };
    __half* xp    = (__half*)carve((size_t)M_ * 512 * 2 + 8192);  // 134 MB gate stream + prefetch pad
    __half* h2    = (__half*)carve((size_t)M_ * 128 * 2);         // 33.5 MB
    __half* W0b   = (__half*)carve(512 * 32 * 2);
    __half* W1b   = (__half*)carve(512 * 128 * 2);
    __half* Whh0h = (__half*)carve(512 * 128 * 2);
    __half* Whh1h = (__half*)carve(512 * 128 * 2);
    __half* Wc16  = (__half*)carve(64 * 128 * 2);
    float*  b0    = (float*)carve(512 * 4);
    float*  b1    = (float*)carve(512 * 4);
    float*  bc    = (float*)carve(64 * 4);
    unsigned* flags = (unsigned*)carve(64 * 8 * 4);

    hipLaunchKernelGGL(convert_kernel, dim3(4), dim3(256), 0, stream,
                       Wih0, bih0, bhh0, Whh0, Wih1, Whh1, bih1, bhh1, Wl, bl, Wo, bo,
                       W0b, W1b, Whh0h, Whh1h, Wc16, b0, b1, bc);

    hipMemsetAsync(flags, 0, 64 * 8 * 4, stream);  // handshake flags must start at 0 every replay

    hipLaunchKernelGGL(lstm_fused, dim3(128), dim3(512), 0, stream,
                       x, W0b, Whh0h, W1b, Whh1h, b0, b1, xp, h2, flags);

    hipLaunchKernelGGL(head_kernel, dim3(M_ / 64), dim3(256), 0, stream,
                       h2, Wc16, bc, out);
}

// Round 10
// 440.369 us; speedup vs baseline: 1.1579x; 1.1579x over previous
//
#include <hip/hip_runtime.h>
#include <hip/hip_fp16.h>

#define B_ 256
#define T_ 512
#define H_ 128
#define M_ (B_ * T_)  // 131072 rows

typedef _Float16 f16x8 __attribute__((ext_vector_type(8)));
typedef float    f32x4 __attribute__((ext_vector_type(4)));

__device__ __forceinline__ float rcp_f(float a) { return __builtin_amdgcn_rcpf(a); }
__device__ __forceinline__ float sigmoid_f(float a) { return rcp_f(1.f + __expf(-a)); }
__device__ __forceinline__ float tanh_f(float a) { return 1.f - 2.f * rcp_f(__expf(2.f * a) + 1.f); }

// LDS-only barrier: global loads/stores stay in flight (T4: never vmcnt(0) per step).
__device__ __forceinline__ void lds_barrier() {
    asm volatile("s_waitcnt lgkmcnt(0)\n\ts_barrier" ::: "memory");
}

// pin a value into a register: asm "modifies" it, so the compiler cannot
// rematerialize the originating load inside the loop (R8: VGPR=120 < live set).
#define PINV(X) asm volatile("" : "+v"(X))

__device__ __forceinline__ __half cell_update(float g0, float g1, float g2, float g3, float& c) {
    float iv = sigmoid_f(g0), fv = sigmoid_f(g1);
    float gv = tanh_f(g2),   ov = sigmoid_f(g3);
    c = fv * c + iv * gv;
    return __float2half(ov * tanh_f(c));
}

// ---- device-visible (cross-XCD via L3) memory ops: sc0 sc1 ----
__device__ __forceinline__ void store_dwordx2_sc(uint64_t addr, uint2 v) {
    asm volatile("global_store_dwordx2 %0, %1, off sc0 sc1" :: "v"(addr), "v"(v) : "memory");
}
__device__ __forceinline__ void store_flag_sc(uint64_t addr, unsigned v) {
    asm volatile("global_store_dword %0, %1, off sc0 sc1" :: "v"(addr), "v"(v) : "memory");
}
__device__ __forceinline__ unsigned load_flag_sc(uint64_t addr) {
    unsigned v;
    asm volatile("global_load_dword %0, %1, off sc0 sc1\n\ts_waitcnt vmcnt(0)"
                 : "=v"(v) : "v"(addr) : "memory");
    return v;
}
#define LOAD8_SC(dst, addr) \
    asm volatile("global_load_dwordx2 %0, %1, off sc0 sc1" : "=&v"(dst) : "v"(addr) : "memory")

// min over 8 per-wave flags
__device__ __forceinline__ void poll_min8(uint64_t base, unsigned target, int lane) {
    for (;;) {
        unsigned v = 0xFFFFFFFFu;
        if (lane < 8) v = load_flag_sc(base + (uint64_t)lane * 4);
        v = min(v, (unsigned)__shfl_xor((int)v, 1));
        v = min(v, (unsigned)__shfl_xor((int)v, 2));
        v = min(v, (unsigned)__shfl_xor((int)v, 4));
        unsigned seen = (unsigned)__shfl((int)v, 0);
        if (seen >= target) break;
        __builtin_amdgcn_s_sleep(8);
    }
}

#define MFMA16(A, BV, C) __builtin_amdgcn_mfma_f32_16x16x32_f16((A), (BV), (C), 0, 0, 0)
#define MF4(AV, WARR, KT) \
    ac0 = MFMA16(AV, WARR[0][KT], ac0); \
    ac1 = MFMA16(AV, WARR[1][KT], ac1); \
    ac2 = MFMA16(AV, WARR[2][KT], ac2); \
    ac3 = MFMA16(AV, WARR[3][KT], ac3);
#define PF4(AV, KT) \
    px0 = MFMA16(AV, wi[0][KT], px0); \
    px1 = MFMA16(AV, wi[1][KT], px1); \
    px2 = MFMA16(AV, wi[2][KT], px2); \
    px3 = MFMA16(AV, wi[3][KT], px3);

// ---------- one-time conversions ----------
__global__ __launch_bounds__(256)
void convert_kernel(const float* __restrict__ Wih0, const float* __restrict__ bih0, const float* __restrict__ bhh0,
                    const float* __restrict__ Whh0, const float* __restrict__ Wih1, const float* __restrict__ Whh1,
                    const float* __restrict__ bih1, const float* __restrict__ bhh1,
                    const float* __restrict__ Wl, const float* __restrict__ bl,
                    const float* __restrict__ Wo, const float* __restrict__ bo,
                    __half* __restrict__ W0b, __half* __restrict__ W1b,
                    __half* __restrict__ Whh0h, __half* __restrict__ Whh1h,
                    __half* __restrict__ Wc16, float* __restrict__ b0, float* __restrict__ b1,
                    float* __restrict__ bc)
{
    const int tid = threadIdx.x, bid = blockIdx.x;
    if (bid == 0) {
        for (int i = tid; i < 512; i += 256) { b0[i] = bih0[i] + bhh0[i]; b1[i] = bih1[i] + bhh1[i]; }
        for (int i = tid; i < 512 * 32; i += 256) {
            int r = i >> 5, k = i & 31;
            W0b[i] = __float2half(k < 30 ? Wih0[r * 30 + k] : 0.f);
        }
        for (int i = tid; i < 64 * 128; i += 256) {
            int j = i >> 7, k = i & 127;
            float a = 0.f;
            if (j < 63) for (int m = 0; m < 84; ++m) a += Wo[j * 84 + m] * Wl[m * 128 + k];
            Wc16[i] = __float2half(a);
        }
        if (tid < 64) {
            float a = 0.f;
            if (tid < 63) { a = bo[tid]; for (int m = 0; m < 84; ++m) a += Wo[tid * 84 + m] * bl[m]; }
            bc[tid] = a;
        }
    } else if (bid == 1) {
        for (int i = tid; i < 512 * 128; i += 256) W1b[i] = __float2half(Wih1[i]);
    } else if (bid == 2) {
        for (int i = tid; i < 512 * 128; i += 256) Whh0h[i] = __float2half(Whh0[i]);
    } else {
        for (int i = tid; i < 512 * 128; i += 256) Whh1h[i] = __float2half(Whh1[i]);
    }
}

// ---------- fused dual-layer recurrence (R8 structure + batched xp1 GEMM) ----------
// blocks [0,64):   layer-0 rec (20 MFMA/step) + per-16-step full-util xp1 GEMM from LDS h1 ring
// blocks [64,128): layer-1 rec, 8-deep counted-vmcnt xp1 consumption
__global__ __launch_bounds__(512, 2)
void lstm_fused(const float* __restrict__ x,
                const __half* __restrict__ W0b, const __half* __restrict__ Whh0h,
                const __half* __restrict__ W1b, const __half* __restrict__ Whh1h,
                const float* __restrict__ b0, const float* __restrict__ b1,
                __half* __restrict__ xp, __half* __restrict__ h2g,
                unsigned* __restrict__ flags)
{
    const int bid = blockIdx.x;
    const bool producer = bid < 64;
    const int g = bid & 63;           // batch group: batches 4g..4g+3
    const int tid = threadIdx.x;
    const int w = tid >> 6;           // wave -> units 16w..16w+15
    const int lane = tid & 63;
    const int l15 = lane & 15, qg = lane >> 4;
    const int j = w * 16 + l15;       // this lane's unit
    const int r = l15 >> 2;           // A-row batch (duplicated 4x -> LDS broadcast)

    __shared__ __align__(16) char hist[32 * 1280];   // producer h1 ring: [32 steps][4 b x 320B]
    __shared__ __align__(16) char hbuf_s[2][1280];   // consumer h2 tile
    __shared__ __align__(16) __half xl[4][129][32];  // producer x chunk
    char* const hb0 = hbuf_s[0];
    char* const hb1 = hbuf_s[1];

    const int ro0 = r * 320 + 0 * 64 + qg * 16;
    const int ro1 = r * 320 + 1 * 64 + qg * 16;
    const int ro2 = r * 320 + 2 * 64 + qg * 16;
    const int ro3 = r * 320 + 3 * 64 + qg * 16;
    const int wo  = qg * 320 + j * 2;

    for (int i = tid; i < 10240; i += 512) ((unsigned*)hist)[i] = 0;   // h1(-1)=0
    for (int i = tid; i < 320; i += 512) ((unsigned*)hb0)[i] = 0;      // h2(-1)=0

    const uint64_t fb = (uint64_t)(uintptr_t)flags;
    const uint64_t flagbase = fb + (uint64_t)(g * 8) * 4;
    float c = 0.f;

    if (producer) {
        float bias4[4], b14[4];
        f16x8 wx[4], wb[4][4], wi[4][4];
#pragma unroll
        for (int q = 0; q < 4; ++q) {
            bias4[q] = b0[q * 128 + j];
            b14[q]   = b1[q * 128 + j];
            wx[q] = *reinterpret_cast<const f16x8*>(W0b + (size_t)(q * 128 + j) * 32 + qg * 8);
            PINV(wx[q]); PINV(bias4[q]); PINV(b14[q]);
#pragma unroll
            for (int kt = 0; kt < 4; ++kt) {
                wb[q][kt] = *reinterpret_cast<const f16x8*>(Whh0h + (size_t)(q * 128 + j) * 128 + kt * 32 + qg * 8);
                wi[q][kt] = *reinterpret_cast<const f16x8*>(W1b   + (size_t)(q * 128 + j) * 128 + kt * 32 + qg * 8);
                PINV(wb[q][kt]); PINV(wi[q][kt]);
            }
        }
        // zero x padding cols once
        for (int idx = tid; idx < 1024; idx += 512) {
            int b4 = idx >> 8, rest = idx & 255;
            xl[b4][rest >> 1][30 + (rest & 1)] = __float2half(0.f);
        }
        const uint64_t pflag = flagbase + (uint64_t)w * 4;
        const uint64_t xpj = (uint64_t)(uintptr_t)xp + ((uint64_t)(4 * j) << 1);
        const char* xlb = (const char*)xl;
        const int xro = r * 8256 + qg * 16;
        __syncthreads();

        // full-utilization xp1 GEMM for chunk cc2 (16 steps x 4 batches = 64 A-rows)
        auto xp1_gemm = [&](int cc2) {
#pragma unroll
            for (int rt = 0; rt < 4; ++rt) {
                const int row = rt * 16 + l15;
                const char* ap = hist + (((cc2 * 16 + (row >> 2)) & 31) * 1280 + (row & 3) * 320 + qg * 16);
                f16x8 h0_ = *(const f16x8*)(ap + 0);
                f16x8 h1_ = *(const f16x8*)(ap + 64);
                f16x8 h2_ = *(const f16x8*)(ap + 128);
                f16x8 h3_ = *(const f16x8*)(ap + 192);
                f32x4 px0 = (f32x4){b14[0], b14[0], b14[0], b14[0]};
                f32x4 px1 = (f32x4){b14[1], b14[1], b14[1], b14[1]};
                f32x4 px2 = (f32x4){b14[2], b14[2], b14[2], b14[2]};
                f32x4 px3 = (f32x4){b14[3], b14[3], b14[3], b14[3]};
                PF4(h0_, 0) PF4(h1_, 1) PF4(h2_, 2) PF4(h3_, 3)
#pragma unroll
                for (int r4 = 0; r4 < 4; ++r4) {
                    const int ro_ = rt * 16 + qg * 4 + r4;
                    const int tglob = cc2 * 16 + (ro_ >> 2);
                    const int b2 = ro_ & 3;
                    __half2 lo_ = __floats2half2_rn(px0[r4], px1[r4]);
                    __half2 hi_ = __floats2half2_rn(px2[r4], px3[r4]);
                    uint2 pk_;
                    pk_.x = __builtin_bit_cast(unsigned, lo_);
                    pk_.y = __builtin_bit_cast(unsigned, hi_);
                    store_dwordx2_sc(xpj + ((uint64_t)((g * 4 + b2) * T_ + tglob) << 10), pk_);
                }
            }
        };

#define PSTEP(TT) do {                                                          \
        const int t_ = (TT);                                                    \
        const char* rp_ = hist + (((t_ + 31) & 31) * 1280);                     \
        f16x8 a0_ = *(const f16x8*)(rp_ + ro0);                                 \
        f16x8 a1_ = *(const f16x8*)(rp_ + ro1);                                 \
        f16x8 a2_ = *(const f16x8*)(rp_ + ro2);                                 \
        f16x8 a3_ = *(const f16x8*)(rp_ + ro3);                                 \
        f16x8 ax_ = *(const f16x8*)(xlb + (xro + (t_ & 127) * 64));             \
        f32x4 ac0 = (f32x4){bias4[0], 0.f, 0.f, 0.f};                           \
        f32x4 ac1 = (f32x4){bias4[1], 0.f, 0.f, 0.f};                           \
        f32x4 ac2 = (f32x4){bias4[2], 0.f, 0.f, 0.f};                           \
        f32x4 ac3 = (f32x4){bias4[3], 0.f, 0.f, 0.f};                           \
        ac0 = MFMA16(ax_, wx[0], ac0); ac1 = MFMA16(ax_, wx[1], ac1);           \
        ac2 = MFMA16(ax_, wx[2], ac2); ac3 = MFMA16(ax_, wx[3], ac3);           \
        MF4(a0_, wb, 0) MF4(a1_, wb, 1) MF4(a2_, wb, 2) MF4(a3_, wb, 3)         \
        __half hh_ = cell_update(ac0[0], ac1[0], ac2[0], ac3[0], c);            \
        *(__half*)(hist + ((t_ & 31) * 1280 + qg * 320 + j * 2)) = hh_;         \
        if ((t_ & 7) == 7) {                                                    \
            asm volatile("s_waitcnt vmcnt(0)" ::: "memory");                    \
            if (lane == 0) store_flag_sc(pflag, (unsigned)(t_ + 1));            \
        }                                                                       \
        lds_barrier();                                                          \
    } while (0)

        for (int xc = 0; xc < 4; ++xc) {
#pragma unroll 1
            for (int b4 = 0; b4 < 4; ++b4) {
                const float* src = x + ((size_t)(g * 4 + b4) * T_ + xc * 128) * 30;
                for (int idx = tid; idx < 3840; idx += 512) {
                    int tt = idx / 30, ii = idx - tt * 30;
                    xl[b4][tt][ii] = __float2half(src[idx]);
                }
            }
            __syncthreads();
#pragma unroll 1
            for (int sc = 0; sc < 8; ++sc) {
                const int cc = xc * 8 + sc;
                if (cc > 0) xp1_gemm(cc - 1);
                const int tb = cc * 16;
                PSTEP(tb + 0);  PSTEP(tb + 1);  PSTEP(tb + 2);  PSTEP(tb + 3);
                PSTEP(tb + 4);  PSTEP(tb + 5);  PSTEP(tb + 6);  PSTEP(tb + 7);
                PSTEP(tb + 8);  PSTEP(tb + 9);  PSTEP(tb + 10); PSTEP(tb + 11);
                PSTEP(tb + 12); PSTEP(tb + 13); PSTEP(tb + 14); PSTEP(tb + 15);
            }
        }
        xp1_gemm(31);                                   // epilogue chunk
        asm volatile("s_waitcnt vmcnt(0)" ::: "memory");
        if (lane == 0) store_flag_sc(pflag, 999u);
    } else {
        // ================= consumer: layer-1 recurrence =================
        f16x8 wb[4][4];
#pragma unroll
        for (int q = 0; q < 4; ++q)
#pragma unroll
            for (int kt = 0; kt < 4; ++kt) {
                wb[q][kt] = *reinterpret_cast<const f16x8*>(Whh1h + (size_t)(q * 128 + j) * 128 + kt * 32 + qg * 8);
                PINV(wb[q][kt]);
            }
        const int b = g * 4 + qg;
        const uint64_t xpcb = (uint64_t)(uintptr_t)xp + ((uint64_t)(((size_t)b * T_) * 512 + 4 * j) << 1);
        __half* h2p = h2g + ((size_t)b * T_) * H_ + j;
        uint2 xq0, xq1, xq2, xq3, xq4, xq5, xq6, xq7;
        __syncthreads();

// 2 vmem ops/step (1 load + 1 h2 store), 8-deep lead: vmcnt(15) forces L(t) complete at t.
#define CSTEP(TT, XQ) do {                                                      \
        const int t_ = (TT);                                                    \
        const char* rp_ = (t_ & 1) ? hb1 : hb0;                                 \
        char* wp_ = (t_ & 1) ? hb0 : hb1;                                       \
        asm volatile("s_waitcnt vmcnt(15)" ::: "memory");                       \
        __builtin_amdgcn_sched_barrier(0);                                      \
        float2 flo = __half22float2(__builtin_bit_cast(__half2, XQ.x));         \
        float2 fhi = __half22float2(__builtin_bit_cast(__half2, XQ.y));         \
        LOAD8_SC(XQ, xpcb + (uint64_t)(t_ + 8) * 1024);                         \
        f16x8 a0_ = *(const f16x8*)(rp_ + ro0);                                 \
        f16x8 a1_ = *(const f16x8*)(rp_ + ro1);                                 \
        f16x8 a2_ = *(const f16x8*)(rp_ + ro2);                                 \
        f16x8 a3_ = *(const f16x8*)(rp_ + ro3);                                 \
        f32x4 ac0 = (f32x4){flo.x, 0.f, 0.f, 0.f};                              \
        f32x4 ac1 = (f32x4){flo.y, 0.f, 0.f, 0.f};                              \
        f32x4 ac2 = (f32x4){fhi.x, 0.f, 0.f, 0.f};                              \
        f32x4 ac3 = (f32x4){fhi.y, 0.f, 0.f, 0.f};                              \
        MF4(a0_, wb, 0) MF4(a1_, wb, 1) MF4(a2_, wb, 2) MF4(a3_, wb, 3)         \
        __half hh_ = cell_update(ac0[0], ac1[0], ac2[0], ac3[0], c);            \
        *(__half*)(wp_ + wo) = hh_;                                             \
        h2p[(size_t)t_ * H_] = hh_;                                             \
        lds_barrier();                                                          \
    } while (0)

        for (int tg = 0; tg < T_; tg += 16) {
            // xp1 chunk (tg/16)+1 is stored at start of chunk (tg/16)+2, drained by flag tg+40.
            unsigned target = (tg + 40 <= 512) ? (unsigned)(tg + 40) : 999u;
            poll_min8(flagbase, target, lane);
            if (tg == 0) {  // preload 8-deep ring, drain once
                LOAD8_SC(xq0, xpcb + 0 * 1024); LOAD8_SC(xq1, xpcb + 1 * 1024);
                LOAD8_SC(xq2, xpcb + 2 * 1024); LOAD8_SC(xq3, xpcb + 3 * 1024);
                LOAD8_SC(xq4, xpcb + 4 * 1024); LOAD8_SC(xq5, xpcb + 5 * 1024);
                LOAD8_SC(xq6, xpcb + 6 * 1024); LOAD8_SC(xq7, xpcb + 7 * 1024);
                asm volatile("s_waitcnt vmcnt(0)" ::: "memory");
                __builtin_amdgcn_sched_barrier(0);
            }
            CSTEP(tg + 0, xq0);  CSTEP(tg + 1, xq1);  CSTEP(tg + 2, xq2);  CSTEP(tg + 3, xq3);
            CSTEP(tg + 4, xq4);  CSTEP(tg + 5, xq5);  CSTEP(tg + 6, xq6);  CSTEP(tg + 7, xq7);
            CSTEP(tg + 8, xq0);  CSTEP(tg + 9, xq1);  CSTEP(tg + 10, xq2); CSTEP(tg + 11, xq3);
            CSTEP(tg + 12, xq4); CSTEP(tg + 13, xq5); CSTEP(tg + 14, xq6); CSTEP(tg + 15, xq7);
        }
    }
}

// ---------- head: out = h2 @ Wc^T + bc (63 cols, f32) ----------
__global__ __launch_bounds__(256, 4)
void head_kernel(const __half* __restrict__ in, const __half* __restrict__ W16,
                 const float* __restrict__ bias, float* __restrict__ outp)
{
    constexpr int KK = 128;
    const int lane = threadIdx.x & 63;
    const int wn = threadIdx.x >> 6;
    const int rowbase = blockIdx.x * 64;  // ROWT=4
    const int colbase = wn * 16;
    const int l15 = lane & 15, lk = (lane >> 4) * 8;

    float bcol = bias[colbase + l15];
    f32x4 acc[4];
#pragma unroll
    for (int rt = 0; rt < 4; ++rt) acc[rt] = (f32x4){0.f, 0.f, 0.f, 0.f};

#pragma unroll
    for (int kt = 0; kt < 4; ++kt) {
        f16x8 bv = *reinterpret_cast<const f16x8*>(W16 + (size_t)(colbase + l15) * KK + kt * 32 + lk);
#pragma unroll
        for (int rt = 0; rt < 4; ++rt) {
            f16x8 a = *reinterpret_cast<const f16x8*>(in + (size_t)(rowbase + rt * 16 + l15) * KK + kt * 32 + lk);
            acc[rt] = __builtin_amdgcn_mfma_f32_16x16x32_f16(a, bv, acc[rt], 0, 0, 0);
        }
    }
    const int col = colbase + l15;
#pragma unroll
    for (int rt = 0; rt < 4; ++rt)
#pragma unroll
        for (int rr = 0; rr < 4; ++rr) {
            const int row = rowbase + rt * 16 + (lane >> 4) * 4 + rr;
            if (col < 63) outp[(size_t)row * 63 + col] = acc[rt][rr] + bcol;
        }
}

extern "C" void kernel_launch(void* const* d_in, const int* in_sizes, int n_in,
                              void* d_out, int out_size, void* d_ws, size_t ws_size,
                              hipStream_t stream)
{
    const float* x    = (const float*)d_in[0];
    const float* Wih0 = (const float*)d_in[1];
    const float* Whh0 = (const float*)d_in[2];
    const float* bih0 = (const float*)d_in[3];
    const float* bhh0 = (const float*)d_in[4];
    const float* Wih1 = (const float*)d_in[5];
    const float* Whh1 = (const float*)d_in[6];
    const float* bih1 = (const float*)d_in[7];
    const float* bhh1 = (const float*)d_in[8];
    const float* Wl   = (const float*)d_in[9];
    const float* bl   = (const float*)d_in[10];
    const float* Wo   = (const float*)d_in[11];
    const float* bo   = (const float*)d_in[12];
    float* out = (float*)d_out;

    char* ws = (char*)d_ws;
    size_t off = 0;
    auto carve = [&](size_t bytes) { void* p = ws + off; off += (bytes + 255) & ~(size_t)255; return p; };
    __half* xp    = (__half*)carve((size_t)M_ * 512 * 2 + 16384);  // gate stream + prefetch pad
    __half* h2    = (__half*)carve((size_t)M_ * 128 * 2);          // 33.5 MB
    __half* W0b   = (__half*)carve(512 * 32 * 2);
    __half* W1b   = (__half*)carve(512 * 128 * 2);
    __half* Whh0h = (__half*)carve(512 * 128 * 2);
    __half* Whh1h = (__half*)carve(512 * 128 * 2);
    __half* Wc16  = (__half*)carve(64 * 128 * 2);
    float*  b0    = (float*)carve(512 * 4);
    float*  b1    = (float*)carve(512 * 4);
    float*  bc    = (float*)carve(64 * 4);
    unsigned* flags = (unsigned*)carve(2048 * 4);

    hipLaunchKernelGGL(convert_kernel, dim3(4), dim3(256), 0, stream,
                       Wih0, bih0, bhh0, Whh0, Wih1, Whh1, bih1, bhh1, Wl, bl, Wo, bo,
                       W0b, W1b, Whh0h, Whh1h, Wc16, b0, b1, bc);

    hipMemsetAsync(flags, 0, 2048 * 4, stream);  // flags must start at 0 every replay

    hipLaunchKernelGGL(lstm_fused, dim3(128), dim3(512), 0, stream,
                       x, W0b, Whh0h, W1b, Whh1h, b0, b1, xp, h2, flags);

    hipLaunchKernelGGL(head_kernel, dim3(M_ / 64), dim3(256), 0, stream,
                       h2, Wc16, bc, out);
}